// Round 8
// baseline (234.044 us; speedup 1.0000x reference)
//
#include <hip/hip_runtime.h>
#include <hip/hip_bf16.h>

// Problem constants
#define TT   20
#define TS   19          // T-1 steps
#define BB   16
#define HH   128
#define WW   128
#define CINN 2
#define CHN  64
#define NOUT 10
#define BETA 0.9f
#define THRV 1.0f

#define SPIKESUM_ELEMS (TS*BB*CHN)           // 19,456 floats
#define SPIKESUM_BYTES (SPIKESUM_ELEMS*4)    // 77,824 B

#define LROWD  68                             // dwords per plane row (66 + 2 pad)
#define NPAIR  264                            // 4 rows x 66 pixel-pairs per t

typedef __attribute__((ext_vector_type(8))) short short8;
typedef __attribute__((ext_vector_type(4))) float float4v;
typedef __attribute__((ext_vector_type(4))) int   int4v;

// round-to-nearest-even fp32 -> bf16 bits
__device__ __forceinline__ unsigned rne16(float f) {
    unsigned u = __float_as_uint(f);
    return (u + 0x7fffu + ((u >> 16) & 1u)) >> 16;
}
__device__ __forceinline__ float b2f(unsigned us) {
    return __uint_as_float(us << 16);
}

// ---------------------------------------------------------------------------
// Fused flow-diff + 3x3 conv (bf16-split MFMA) + beta-scaled LIF + counts.
//
// beta-scaling: W_t = V_t * beta^-t  =>  W_t = W_{t-1} + beta^-t * u_t ;
// spike iff W > ct (ct = beta^-t), reset W -= ct. So the MFMA accumulates
// straight into W (C operand = W, in place): the leak costs ZERO VALU ops.
// The beta^-t scale is applied in the pack (2 muls/thread) and to the
// wave-uniform threshold/bias-tap constants.
//
// Block = 2 rows x 64 px, all 64 channels; wave = 16 px x 2 row-sets.
// Pipelined t-loop, double-buffered two-plane LDS (hi/lo bf16 pairs), one
// barrier per t; x register-carried (rb=ra rotation, one float2 load/thread).
// k-remap: quad = ky, j = kx*2+ci (j<6); k=24 tap: A = ct (split), B = bias
// (split) — both in dword0 low half of quad 3.
// u = Ah*Bh + Al*Bh + Ah*Bl (drops Alo*Blo ~ 2^-16 relative).
// C/D layout: row(pixel) = q*4+reg, col(channel-in-group) = lane&15.
// ---------------------------------------------------------------------------
__global__ __launch_bounds__(256, 4) void lif_main(const float* __restrict__ x,
                                                   const float* __restrict__ w_conv,
                                                   const float* __restrict__ b_conv,
                                                   float* __restrict__ spikesum) {
    __shared__ unsigned lds2[2][2][4 * LROWD];   // [buf][plane][row*68+dw] = 4352 B

    const float2* xp2 = (const float2*)x;        // pixel-granular (ci pair)
    const int FRAME2  = BB * HH * WW;            // float2s per time slice

    const int tid  = threadIdx.x;
    const int lane = tid & 63;
    const int wv   = __builtin_amdgcn_readfirstlane(tid >> 6); // uniform 0..3
    const int bx   = blockIdx.x;                 // 0..1 : pixel half
    const int r0   = blockIdx.y << 1;            // first of 2 output rows
    const int bz   = blockIdx.z;                 // batch
    const int q    = lane >> 4;                  // quad
    const int col  = lane & 15;
    const int relpx = (wv << 4) + col;           // 0..63 pixel within tile

    // ---- t-invariant staging slots (pair = one pixel, both ci)
    const int  pr0 = tid;
    const int  ra0r = pr0 / 66, ra0d = pr0 - ra0r * 66;
    const int  y0s  = r0 - 1 + ra0r;
    const int  px0s = (bx << 6) - 1 + ra0d;
    const bool val0 = ((unsigned)y0s < (unsigned)HH) && ((unsigned)px0s < (unsigned)WW);
    const int  off0 = val0 ? (y0s * WW + px0s) : 0;
    const int  ls0  = ra0r * LROWD + ra0d;

    const bool act1 = (tid < NPAIR - 256);
    const int  pr1 = 256 + tid;
    const int  ra1r = pr1 / 66, ra1d = pr1 - ra1r * 66;
    const int  y1s  = r0 - 1 + ra1r;
    const int  px1s = (bx << 6) - 1 + ra1d;
    const bool val1 = act1 && ((unsigned)y1s < (unsigned)HH) && ((unsigned)px1s < (unsigned)WW);
    const int  off1 = val1 ? (y1s * WW + px1s) : 0;
    const int  ls1  = ra1r * LROWD + ra1d;

    // ---- B fragments: k = q*8+j ; q<3,j<6: weights ; q==3,j==0: bias tap
    short8 Bh[4], Bl[4];
#pragma unroll
    for (int cg = 0; cg < 4; ++cg) {
        int hi_i[4] = {0, 0, 0, 0}, lo_i[4] = {0, 0, 0, 0};
        if (q < 3) {
#pragma unroll
            for (int j = 0; j < 6; ++j) {
                float w = w_conv[((q * 3 + (j >> 1)) * 2 + (j & 1)) * CHN + cg * 16 + col];
                unsigned hs = rne16(w);
                unsigned ls = rne16(w - b2f(hs));
                hi_i[j >> 1] |= (int)(hs << (16 * (j & 1)));
                lo_i[j >> 1] |= (int)(ls << (16 * (j & 1)));
            }
        } else {
            float bb = b_conv[cg * 16 + col];
            unsigned hs = rne16(bb);
            unsigned ls = rne16(bb - b2f(hs));
            hi_i[0] = (int)hs;                   // j=0 -> k=24, low half
            lo_i[0] = (int)ls;
        }
        int4v hv = {hi_i[0], hi_i[1], hi_i[2], hi_i[3]};
        int4v lv = {lo_i[0], lo_i[1], lo_i[2], lo_i[3]};
        Bh[cg] = __builtin_bit_cast(short8, hv);
        Bl[cg] = __builtin_bit_cast(short8, lv);
    }

    float4v W0[4], W1[4];                        // beta-scaled membrane
#pragma unroll
    for (int cg = 0; cg < 4; ++cg) {
        W0[cg] = (float4v){0.f, 0.f, 0.f, 0.f};
        W1[cg] = (float4v){0.f, 0.f, 0.f, 0.f};
    }

    // ---- preheader: rb = x[0], ra = x[1]
    float2 ra_0 = {0.f, 0.f}, rb_0 = {0.f, 0.f};
    float2 ra_1 = {0.f, 0.f}, rb_1 = {0.f, 0.f};
    {
        const int s2a = bz * HH * WW;             // slice 0 base (float2)
        if (val0) { rb_0 = xp2[s2a + off0]; ra_0 = xp2[s2a + FRAME2 + off0]; }
        if (val1) { rb_1 = xp2[s2a + off1]; ra_1 = xp2[s2a + FRAME2 + off1]; }
    }

    float ct = 1.f;                               // beta^-t
    for (int t = 0; t < TS; ++t) {
        const float nct = -ct;
        // wave-uniform split of ct for the bias tap
        const unsigned cth = rne16(ct);
        const unsigned ctl = __float_as_uint(ct - b2f(cth)) >> 16;

        // ---- pack flow*ct = (ra - rb)*ct into two bf16 planes
        unsigned* hiP = &lds2[t & 1][0][0];
        unsigned* loP = &lds2[t & 1][1][0];
        {
            float d0 = (ra_0.x - rb_0.x) * ct;    // invalid slots stay 0
            float d1 = (ra_0.y - rb_0.y) * ct;
            unsigned h0 = rne16(d0), h1 = rne16(d1);
            unsigned l0 = __float_as_uint(d0 - b2f(h0)) >> 16;
            unsigned l1 = __float_as_uint(d1 - b2f(h1)) >> 16;
            hiP[ls0] = h0 | (h1 << 16);
            loP[ls0] = l0 | (l1 << 16);
        }
        if (act1) {
            float d0 = (ra_1.x - rb_1.x) * ct;
            float d1 = (ra_1.y - rb_1.y) * ct;
            unsigned h0 = rne16(d0), h1 = rne16(d1);
            unsigned l0 = __float_as_uint(d0 - b2f(h0)) >> 16;
            unsigned l1 = __float_as_uint(d1 - b2f(h1)) >> 16;
            hiP[ls1] = h0 | (h1 << 16);
            loP[ls1] = l0 | (l1 << 16);
        }
        __syncthreads();

        // ---- rotate and issue loads for t+1 (x slice t+2)
        if (t + 1 < TS) {
            const int s2n = ((t + 2) * BB + bz) * (HH * WW);
            rb_0 = ra_0; rb_1 = ra_1;
            if (val0) ra_0 = xp2[s2n + off0];
            if (val1) ra_1 = xp2[s2n + off1];
        }

        // ---- A fragments: 3 dwords per plane per row-set (q<3); tap for q==3
        unsigned h0, h1, h2, l0, l1, l2, h3, h4, h5, l3, l4, l5;
        if (q < 3) {
            const unsigned* hp = hiP + q * LROWD + relpx;
            const unsigned* lp = loP + q * LROWD + relpx;
            h0 = hp[0]; h1 = hp[1]; h2 = hp[2];
            l0 = lp[0]; l1 = lp[1]; l2 = lp[2];
            h3 = hp[LROWD]; h4 = hp[LROWD + 1]; h5 = hp[LROWD + 2];
            l3 = lp[LROWD]; l4 = lp[LROWD + 1]; l5 = lp[LROWD + 2];
        } else {
            h0 = cth; l0 = ctl; h3 = cth; l3 = ctl;   // k=24 tap = ct (split)
            h1 = h2 = l1 = l2 = 0;
            h4 = h5 = l4 = l5 = 0;
        }
        int4v a0h = {(int)h0, (int)h1, (int)h2, 0};
        int4v a0l = {(int)l0, (int)l1, (int)l2, 0};
        int4v a1h = {(int)h3, (int)h4, (int)h5, 0};
        int4v a1l = {(int)l3, (int)l4, (int)l5, 0};
        short8 A0h = __builtin_bit_cast(short8, a0h);
        short8 A0l = __builtin_bit_cast(short8, a0l);
        short8 A1h = __builtin_bit_cast(short8, a1h);
        short8 A1l = __builtin_bit_cast(short8, a1l);

        // ---- conv accumulates straight into W (C operand) + lean LIF
        float c0 = 0.f, c1 = 0.f, c2 = 0.f, c3 = 0.f;
#pragma unroll
        for (int cg = 0; cg < 4; ++cg) {
            float4v u0 = W0[cg];
            float4v u1 = W1[cg];
            u0 = __builtin_amdgcn_mfma_f32_16x16x32_bf16(A0h, Bh[cg], u0, 0, 0, 0);
            u1 = __builtin_amdgcn_mfma_f32_16x16x32_bf16(A1h, Bh[cg], u1, 0, 0, 0);
            u0 = __builtin_amdgcn_mfma_f32_16x16x32_bf16(A0l, Bh[cg], u0, 0, 0, 0);
            u1 = __builtin_amdgcn_mfma_f32_16x16x32_bf16(A1l, Bh[cg], u1, 0, 0, 0);
            u0 = __builtin_amdgcn_mfma_f32_16x16x32_bf16(A0h, Bl[cg], u0, 0, 0, 0);
            u1 = __builtin_amdgcn_mfma_f32_16x16x32_bf16(A1h, Bl[cg], u1, 0, 0, 0);
            float c = 0.f;
#pragma unroll
            for (int r = 0; r < 4; ++r) {
                float w0 = u0[r];
                float s0 = (w0 > ct) ? 1.f : 0.f;
                u0[r] = fmaf(s0, nct, w0);
                c += s0;
                float w1 = u1[r];
                float s1 = (w1 > ct) ? 1.f : 0.f;
                u1[r] = fmaf(s1, nct, w1);
                c += s1;
            }
            W0[cg] = u0;
            W1[cg] = u1;
            c += __shfl_xor(c, 16);
            c += __shfl_xor(c, 32);
            if (cg == 0) c0 = c; else if (cg == 1) c1 = c;
            else if (cg == 2) c2 = c; else c3 = c;
        }
        float my = (q == 0) ? c0 : (q == 1) ? c1 : (q == 2) ? c2 : c3;
        // channel = q*16 + col = lane ; float atomic is exact for integers
        atomicAdd(&spikesum[(t * BB + bz) * CHN + lane], my);

        ct *= (1.0f / BETA);
    }
}

// ---------------------------------------------------------------------------
// head: one block per batch b. Computes logits[t][b][:], readout[b][:]
// (mean over t), and (block 0 only) sr. Writes every out element -> no
// memset(out), no atomics.
// ---------------------------------------------------------------------------
__global__ __launch_bounds__(256) void head_kernel(const float* __restrict__ spikesum,
                                                   const float* __restrict__ w_head,
                                                   const float* __restrict__ b_head,
                                                   float* __restrict__ out) {
    __shared__ float lg_s[TS][NOUT];
    const int b = blockIdx.x, tid = threadIdx.x;

    if (tid < TS * NOUT) {
        const int t = tid / NOUT, o = tid - t * NOUT;
        const float* cnt = spikesum + (t * BB + b) * CHN;
        float acc = 0.f;
#pragma unroll
        for (int ch = 0; ch < CHN; ++ch) acc = fmaf(cnt[ch], w_head[ch * NOUT + o], acc);
        float lg = acc * (1.f / (HH * WW)) + b_head[o];
        out[BB * NOUT + (t * BB + b) * NOUT + o] = lg;
        lg_s[t][o] = lg;
    }
    __syncthreads();
    if (tid < NOUT) {
        float a = 0.f;
#pragma unroll
        for (int t = 0; t < TS; ++t) a += lg_s[t][tid];
        out[b * NOUT + tid] = a * (1.f / TS);
    }
    if (b == 0) {
        float s = 0.f;
        for (int i = tid; i < SPIKESUM_ELEMS; i += 256) s += spikesum[i];
#pragma unroll
        for (int off = 32; off > 0; off >>= 1) s += __shfl_down(s, off);
        __shared__ float red[4];
        if ((tid & 63) == 0) red[tid >> 6] = s;
        __syncthreads();
        if (tid == 0)
            out[BB * NOUT + TS * BB * NOUT] =
                (red[0] + red[1] + red[2] + red[3]) *
                (1.f / ((float)TS * BB * HH * WW * CHN));
    }
}

// ---------------------------------------------------------------------------
extern "C" void kernel_launch(void* const* d_in, const int* in_sizes, int n_in,
                              void* d_out, int out_size, void* d_ws, size_t ws_size,
                              hipStream_t stream) {
    (void)in_sizes; (void)n_in; (void)out_size; (void)ws_size;
    const float* x      = (const float*)d_in[0];
    const float* w_conv = (const float*)d_in[1];
    const float* b_conv = (const float*)d_in[2];
    const float* w_head = (const float*)d_in[3];
    const float* b_head = (const float*)d_in[4];
    float* out      = (float*)d_out;
    float* spikesum = (float*)d_ws;

    (void)hipMemsetAsync(d_ws, 0, SPIKESUM_BYTES, stream);

    lif_main<<<dim3(2, HH / 2, BB), 256, 0, stream>>>(x, w_conv, b_conv, spikesum);
    head_kernel<<<BB, 256, 0, stream>>>(spikesum, w_head, b_head, out);
}

// Round 9
// 209.216 us; speedup vs baseline: 1.1187x; 1.1187x over previous
//
#include <hip/hip_runtime.h>
#include <hip/hip_bf16.h>

// Problem constants
#define TT   20
#define TS   19          // T-1 steps
#define BB   16
#define HH   128
#define WW   128
#define CINN 2
#define CHN  64
#define NOUT 10
#define BETA 0.9f
#define THRV 1.0f

#define SPIKESUM_ELEMS (TS*BB*CHN)           // 19,456 ints
#define SPIKESUM_BYTES (SPIKESUM_ELEMS*4)    // 77,824 B

#define LROWD  72                             // dwords per plane row (66 used + 6 pad)
                                              // 72 mod 32 = 8 -> quad offsets 0/8/16/24:
                                              // exactly 2-way bank aliasing (free)
#define NPAIR  264                            // 4 rows x 66 pixel-pairs staged per t

typedef __attribute__((ext_vector_type(8))) short short8;
typedef __attribute__((ext_vector_type(4))) float float4v;
typedef __attribute__((ext_vector_type(4))) int   int4v;

// round-to-nearest-even fp32 -> bf16 bits
__device__ __forceinline__ unsigned rne16(float f) {
    unsigned u = __float_as_uint(f);
    return (u + 0x7fffu + ((u >> 16) & 1u)) >> 16;
}
__device__ __forceinline__ float b2f(unsigned us) {
    return __uint_as_float(us << 16);
}

// ---------------------------------------------------------------------------
// Fused flow-diff + 3x3 conv (bf16-split MFMA) + LIF scan + spike count.
//
// Block = 2 rows x 64 px, all 64 channels; wave = 16 px x 2 row-sets.
// TWO t-steps per barrier: registers carry x[t], x[t+1], x[t+2] (xa/xb/xc,
// rotation xa<-xc + 2 float2 loads per 2-t iter); both flow slices packed
// into separate LDS t-sub-buffers, ONE __syncthreads per 2 t. Prefetch
// distance = one full 2-t iteration (~2x R7).
//
// C-init is a fresh zero per t (NOT in-place accumulate: R8 showed the
// loop-carried MFMA C chain kills MFMA/VALU overlap, 123->145us).
// k-remap: quad = ky, j = kx*2+ci (j<6). k=24 tap: A = 1.0, B = bias
// (both in dword0 low half of quad 3 - correctly k-aligned, unlike R7).
// u = Ah*Bh + Al*Bh + Ah*Bl (drops Alo*Blo ~ 2^-16 relative).
// C/D layout: row(pixel) = q*4+reg, col(channel-in-group) = lane&15.
// ---------------------------------------------------------------------------
__global__ __launch_bounds__(256, 4) void lif_main(const float* __restrict__ x,
                                                   const float* __restrict__ w_conv,
                                                   const float* __restrict__ b_conv,
                                                   int* __restrict__ spikesum) {
    __shared__ unsigned lds[2][2][2][4 * LROWD]; // [buf][tsub][plane][row*72+dw] = 9216 B

    const float2* xp2 = (const float2*)x;        // pixel-granular (ci pair)

    const int tid  = threadIdx.x;
    const int lane = tid & 63;
    const int wv   = __builtin_amdgcn_readfirstlane(tid >> 6); // uniform 0..3
    const int bx   = blockIdx.x;                 // 0..1 : pixel half
    const int r0   = blockIdx.y << 1;            // first of 2 output rows
    const int bz   = blockIdx.z;                 // batch
    const int q    = lane >> 4;                  // quad
    const int col  = lane & 15;
    const int relpx = (wv << 4) + col;           // 0..63 pixel within tile

    // ---- t-invariant staging slots (pair = one pixel, both ci)
    const int  pr0 = tid;
    const int  ra0r = pr0 / 66, ra0d = pr0 - ra0r * 66;
    const int  y0s  = r0 - 1 + ra0r;
    const int  px0s = (bx << 6) - 1 + ra0d;
    const bool val0 = ((unsigned)y0s < (unsigned)HH) && ((unsigned)px0s < (unsigned)WW);
    const int  off0 = val0 ? (y0s * WW + px0s) : 0;
    const int  ls0  = ra0r * LROWD + ra0d;

    const bool act1 = (tid < NPAIR - 256);       // tid < 8
    const int  pr1 = 256 + tid;
    const int  ra1r = pr1 / 66, ra1d = pr1 - ra1r * 66;
    const int  y1s  = r0 - 1 + ra1r;
    const int  px1s = (bx << 6) - 1 + ra1d;
    const bool val1 = act1 && ((unsigned)y1s < (unsigned)HH) && ((unsigned)px1s < (unsigned)WW);
    const int  off1 = val1 ? (y1s * WW + px1s) : 0;
    const int  ls1  = ra1r * LROWD + ra1d;

    // ---- B fragments: k = q*8+j ; q<3,j<6: weights ; q==3,j==0 (k=24): bias
    short8 Bh[4], Bl[4];
#pragma unroll
    for (int cg = 0; cg < 4; ++cg) {
        int hi_i[4] = {0, 0, 0, 0}, lo_i[4] = {0, 0, 0, 0};
        if (q < 3) {
#pragma unroll
            for (int j = 0; j < 6; ++j) {
                float w = w_conv[((q * 3 + (j >> 1)) * 2 + (j & 1)) * CHN + cg * 16 + col];
                unsigned hs = rne16(w);
                unsigned ls = rne16(w - b2f(hs));
                hi_i[j >> 1] |= (int)(hs << (16 * (j & 1)));
                lo_i[j >> 1] |= (int)(ls << (16 * (j & 1)));
            }
        } else {
            float bb = b_conv[cg * 16 + col];
            unsigned hs = rne16(bb);
            unsigned ls = rne16(bb - b2f(hs));
            hi_i[0] = (int)hs;                   // k=24, low half
            lo_i[0] = (int)ls;
        }
        int4v hv = {hi_i[0], hi_i[1], hi_i[2], hi_i[3]};
        int4v lv = {lo_i[0], lo_i[1], lo_i[2], lo_i[3]};
        Bh[cg] = __builtin_bit_cast(short8, hv);
        Bl[cg] = __builtin_bit_cast(short8, lv);
    }

    float V0[4][4], V1[4][4];                    // membrane, rows r0, r0+1
#pragma unroll
    for (int cg = 0; cg < 4; ++cg)
#pragma unroll
        for (int r = 0; r < 4; ++r) { V0[cg][r] = 0.f; V1[cg][r] = 0.f; }

    // ---- preheader: xa = x[0], xb = x[1], xc = x[2]
    float2 xa_0 = {0.f, 0.f}, xb_0 = {0.f, 0.f}, xc_0 = {0.f, 0.f};
    float2 xa_1 = {0.f, 0.f}, xb_1 = {0.f, 0.f}, xc_1 = {0.f, 0.f};
    {
        const int s0 = (0 * BB + bz) * (HH * WW);
        const int s1 = (1 * BB + bz) * (HH * WW);
        const int s2 = (2 * BB + bz) * (HH * WW);
        if (val0) { xa_0 = xp2[s0 + off0]; xb_0 = xp2[s1 + off0]; xc_0 = xp2[s2 + off0]; }
        if (val1) { xa_1 = xp2[s0 + off1]; xb_1 = xp2[s1 + off1]; xc_1 = xp2[s2 + off1]; }
    }

    // ---- per-t work: A-frag read + 24 MFMA + LIF + count + atomic
    auto process_t = [&](int t, const unsigned* hiP, const unsigned* loP) {
        unsigned h0, h1, h2, l0, l1, l2, h3, h4, h5, l3, l4, l5;
        if (q < 3) {
            const unsigned* hp = hiP + q * LROWD + relpx;
            const unsigned* lp = loP + q * LROWD + relpx;
            h0 = hp[0]; h1 = hp[1]; h2 = hp[2];
            l0 = lp[0]; l1 = lp[1]; l2 = lp[2];
            h3 = hp[LROWD]; h4 = hp[LROWD + 1]; h5 = hp[LROWD + 2];
            l3 = lp[LROWD]; l4 = lp[LROWD + 1]; l5 = lp[LROWD + 2];
        } else {
            h0 = 0x3f80u; l0 = 0; h3 = 0x3f80u; l3 = 0;   // k=24 tap = 1.0
            h1 = h2 = l1 = l2 = 0;
            h4 = h5 = l4 = l5 = 0;
        }
        int4v a0h = {(int)h0, (int)h1, (int)h2, 0};
        int4v a0l = {(int)l0, (int)l1, (int)l2, 0};
        int4v a1h = {(int)h3, (int)h4, (int)h5, 0};
        int4v a1l = {(int)l3, (int)l4, (int)l5, 0};
        short8 A0h = __builtin_bit_cast(short8, a0h);
        short8 A0l = __builtin_bit_cast(short8, a0l);
        short8 A1h = __builtin_bit_cast(short8, a1h);
        short8 A1l = __builtin_bit_cast(short8, a1l);

        int cnt0 = 0, cnt1 = 0, cnt2 = 0, cnt3 = 0;
#pragma unroll
        for (int cg = 0; cg < 4; ++cg) {
            float4v u0 = {0.f, 0.f, 0.f, 0.f};
            float4v u1 = {0.f, 0.f, 0.f, 0.f};
            u0 = __builtin_amdgcn_mfma_f32_16x16x32_bf16(A0h, Bh[cg], u0, 0, 0, 0);
            u1 = __builtin_amdgcn_mfma_f32_16x16x32_bf16(A1h, Bh[cg], u1, 0, 0, 0);
            u0 = __builtin_amdgcn_mfma_f32_16x16x32_bf16(A0l, Bh[cg], u0, 0, 0, 0);
            u1 = __builtin_amdgcn_mfma_f32_16x16x32_bf16(A1l, Bh[cg], u1, 0, 0, 0);
            u0 = __builtin_amdgcn_mfma_f32_16x16x32_bf16(A0h, Bl[cg], u0, 0, 0, 0);
            u1 = __builtin_amdgcn_mfma_f32_16x16x32_bf16(A1h, Bl[cg], u1, 0, 0, 0);
            int c = 0;
#pragma unroll
            for (int r = 0; r < 4; ++r) {
                float v0 = fmaf(BETA, V0[cg][r], u0[r]);
                bool  s0 = v0 > THRV;
                c += s0 ? 1 : 0;
                V0[cg][r] = s0 ? (v0 - THRV) : v0;
                float v1 = fmaf(BETA, V1[cg][r], u1[r]);
                bool  s1 = v1 > THRV;
                c += s1 ? 1 : 0;
                V1[cg][r] = s1 ? (v1 - THRV) : v1;
            }
            c += __shfl_xor(c, 16);
            c += __shfl_xor(c, 32);
            if (cg == 0) cnt0 = c; else if (cg == 1) cnt1 = c;
            else if (cg == 2) cnt2 = c; else cnt3 = c;
        }
        int my = (q == 0) ? cnt0 : (q == 1) ? cnt1 : (q == 2) ? cnt2 : cnt3;
        // channel = q*16 + col = lane
        atomicAdd(&spikesum[(t * BB + bz) * CHN + lane], my);
    };

    // ---- pack helper: d = (n - c) split to hi/lo planes at slot
    auto pack = [&](unsigned* hiP, unsigned* loP, int slot, float2 cu, float2 nx) {
        float d0 = nx.x - cu.x;
        float d1 = nx.y - cu.y;
        unsigned ph0 = rne16(d0), ph1 = rne16(d1);
        unsigned pl0 = rne16(d0 - b2f(ph0)), pl1 = rne16(d1 - b2f(ph1));
        hiP[slot] = ph0 | (ph1 << 16);
        loP[slot] = pl0 | (pl1 << 16);
    };

    for (int t0 = 0; t0 < TS; t0 += 2) {
        const int  buf  = (t0 >> 1) & 1;
        const bool has2 = (t0 + 1 < TS);          // uniform

        // ---- pack flow[t0] = xb - xa ; flow[t0+1] = xc - xb
        unsigned* hi0 = &lds[buf][0][0][0];
        unsigned* lo0 = &lds[buf][0][1][0];
        unsigned* hi1 = &lds[buf][1][0][0];
        unsigned* lo1 = &lds[buf][1][1][0];
        pack(hi0, lo0, ls0, xa_0, xb_0);
        if (act1) pack(hi0, lo0, ls1, xa_1, xb_1);
        if (has2) {
            pack(hi1, lo1, ls0, xb_0, xc_0);
            if (act1) pack(hi1, lo1, ls1, xb_1, xc_1);
        }
        __syncthreads();

        // ---- rotate + issue loads for next 2-t iteration
        if (t0 + 2 < TS) {
            xa_0 = xc_0; xa_1 = xc_1;
            const int sB = ((t0 + 3) * BB + bz) * (HH * WW);
            if (val0) xb_0 = xp2[sB + off0];
            if (val1) xb_1 = xp2[sB + off1];
            if (t0 + 4 < TT) {
                const int sC = ((t0 + 4) * BB + bz) * (HH * WW);
                if (val0) xc_0 = xp2[sC + off0];
                if (val1) xc_1 = xp2[sC + off1];
            }
        }

        // ---- compute both t-steps from LDS
        process_t(t0, hi0, lo0);
        if (has2) process_t(t0 + 1, hi1, lo1);
    }
}

// ---------------------------------------------------------------------------
// head: one block per batch b. Computes logits[t][b][:], readout[b][:]
// (mean over t), and (block 0 only) sr. Writes every out element -> no
// memset(out), no atomics.
// ---------------------------------------------------------------------------
__global__ __launch_bounds__(256) void head_kernel(const int* __restrict__ spikesum,
                                                   const float* __restrict__ w_head,
                                                   const float* __restrict__ b_head,
                                                   float* __restrict__ out) {
    __shared__ float lg_s[TS][NOUT];
    const int b = blockIdx.x, tid = threadIdx.x;

    if (tid < TS * NOUT) {
        const int t = tid / NOUT, o = tid - t * NOUT;
        const int* cnt = spikesum + (t * BB + b) * CHN;
        float acc = 0.f;
#pragma unroll
        for (int ch = 0; ch < CHN; ++ch)
            acc = fmaf((float)cnt[ch], w_head[ch * NOUT + o], acc);
        float lg = acc * (1.f / (HH * WW)) + b_head[o];
        out[BB * NOUT + (t * BB + b) * NOUT + o] = lg;
        lg_s[t][o] = lg;
    }
    __syncthreads();
    if (tid < NOUT) {
        float a = 0.f;
#pragma unroll
        for (int t = 0; t < TS; ++t) a += lg_s[t][tid];
        out[b * NOUT + tid] = a * (1.f / TS);
    }
    if (b == 0) {
        int s = 0;
        for (int i = tid; i < SPIKESUM_ELEMS; i += 256) s += spikesum[i];
#pragma unroll
        for (int off = 32; off > 0; off >>= 1) s += __shfl_down(s, off);
        __shared__ int red[4];
        if ((tid & 63) == 0) red[tid >> 6] = s;
        __syncthreads();
        if (tid == 0)
            out[BB * NOUT + TS * BB * NOUT] =
                (float)(red[0] + red[1] + red[2] + red[3]) *
                (1.f / ((float)TS * BB * HH * WW * CHN));
    }
}

// ---------------------------------------------------------------------------
extern "C" void kernel_launch(void* const* d_in, const int* in_sizes, int n_in,
                              void* d_out, int out_size, void* d_ws, size_t ws_size,
                              hipStream_t stream) {
    (void)in_sizes; (void)n_in; (void)out_size; (void)ws_size;
    const float* x      = (const float*)d_in[0];
    const float* w_conv = (const float*)d_in[1];
    const float* b_conv = (const float*)d_in[2];
    const float* w_head = (const float*)d_in[3];
    const float* b_head = (const float*)d_in[4];
    float* out      = (float*)d_out;
    int*   spikesum = (int*)d_ws;

    (void)hipMemsetAsync(d_ws, 0, SPIKESUM_BYTES, stream);

    lif_main<<<dim3(2, HH / 2, BB), 256, 0, stream>>>(x, w_conv, b_conv, spikesum);
    head_kernel<<<BB, 256, 0, stream>>>(spikesum, w_head, b_head, out);
}